// Round 12
// baseline (588.554 us; speedup 1.0000x reference)
//
#include <hip/hip_runtime.h>
#include <hip/hip_bf16.h>

#define CDIV(a, b) (((a) + (b) - 1) / (b))

typedef __attribute__((ext_vector_type(8))) __bf16 bf16x8;
typedef __attribute__((ext_vector_type(2))) __bf16 bf16x2;
typedef __attribute__((ext_vector_type(4))) float f32x4;

__device__ __forceinline__ float bf2f(unsigned short u) {
  union { unsigned int i; float f; } c; c.i = ((unsigned int)u) << 16; return c.f;
}
__device__ __forceinline__ unsigned short f2bf(float f) {
  union { float f; unsigned int i; } c; c.f = f;
  unsigned int r = c.i + 0x7fffu + ((c.i >> 16) & 1u);
  return (unsigned short)(r >> 16);
}
// two floats -> packed bf16x2 in one u32 (v_cvt_pk_bf16_f32)
__device__ __forceinline__ unsigned int cvt2(float a, float b) {
  bf16x2 v; v[0] = (__bf16)a; v[1] = (__bf16)b;
  union { bf16x2 v; unsigned int u; } c; c.v = v; return c.u;
}
__device__ __forceinline__ unsigned short cvt1(float a) {
  __bf16 b = (__bf16)a;
  union { __bf16 b; unsigned short u; } c; c.b = b; return c.u;
}

// ---- dtype detector: flag=1 if fp32 storage, 0 if bf16 storage ----
__global__ void k_detect(const unsigned short* __restrict__ xq, int nsamp, int* __restrict__ flagp) {
  __shared__ float sm[256];
  int t = threadIdx.x;
  float mx = 0.f;
  for (int i = t; i < nsamp; i += 256) {
    float v = bf2f(xq[i]);
    if (!(v == v)) v = 1e30f;
    mx = fmaxf(mx, fabsf(v));
  }
  sm[t] = mx; __syncthreads();
  for (int o = 128; o > 0; o >>= 1) {
    if (t < o) sm[t] = fmaxf(sm[t], sm[t + o]);
    __syncthreads();
  }
  if (t == 0) *flagp = (sm[0] > 1e6f) ? 1 : 0;
}

// ---- 8 weight transposes + 7 small cvts in ONE dispatch ----
// grid = 128 + 128 + 6*256 + 7 = 1799 blocks of 256 threads.
__global__ void k_wh8(const void* s0, const void* s1, const void* s2, const void* s3,
                      const void* s4, const void* s5, const void* s6, const void* s7,
                      unsigned short* d0, unsigned short* d1, unsigned short* d2,
                      unsigned short* d3, unsigned short* d4, unsigned short* d5,
                      unsigned short* d6, unsigned short* d7,
                      const void* p0, const void* p1, const void* p2, const void* p3,
                      const void* p4, const void* p5, const void* p6,
                      float* f0, float* f1, float* f2, float* f3,
                      float* f4, float* f5, float* f6,
                      const int* __restrict__ flagp) {
  int b = blockIdx.x, t = threadIdx.x;
  if (b >= 1792) {  // cvt tail
    int c = b - 1792;
    const void* s = 0; float* d = 0; int n = 256;
    switch (c) {
      case 0: s = p0; d = f0; break;
      case 1: s = p1; d = f1; break;
      case 2: s = p2; d = f2; break;
      case 3: s = p3; d = f3; break;
      case 4: s = p4; d = f4; break;
      case 5: s = p5; d = f5; break;
      default: s = p6; d = f6; n = 1; break;
    }
    if (t < n) d[t] = (*flagp) ? ((const float*)s)[t] : bf2f(((const unsigned short*)s)[t]);
    return;
  }
  const void* W; unsigned short* Bt; int K; int base;
  if (b < 128)       { W = s0; Bt = d0; K = 128; base = 0; }
  else if (b < 256)  { W = s1; Bt = d1; K = 128; base = 128; }
  else {
    int r = (b - 256) >> 8;       // 0..5
    base = 256 + r * 256; K = 256;
    switch (r) {
      case 0:  W = s2; Bt = d2; break;
      case 1:  W = s3; Bt = d3; break;
      case 2:  W = s4; Bt = d4; break;
      case 3:  W = s5; Bt = d5; break;
      case 4:  W = s6; Bt = d6; break;
      default: W = s7; Bt = d7; break;
    }
  }
  int i = (b - base) * 256 + t;   // < K*256 by grid construction
  int k = i >> 8, n = i & 255;
  float v = (*flagp) ? ((const float*)W)[i] : bf2f(((const unsigned short*)W)[i]);
  Bt[(size_t)n * K + k] = f2bf(v);
}

// ---- x -> bf16 plane ----
__global__ void k_xbf16(const void* __restrict__ x, unsigned short* __restrict__ Xb, int n,
                        const int* __restrict__ flagp) {
  int i = blockIdx.x * 256 + threadIdx.x;
  if (i >= n) return;
  float v = (*flagp) ? ((const float*)x)[i] : bf2f(((const unsigned short*)x)[i]);
  Xb[i] = f2bf(v);
}

__global__ void k_zero_i32(int* p, int n) {
  int i = blockIdx.x * 256 + threadIdx.x;
  if (i < n) p[i] = 0;
}

// ---------------- CSR build ----------------
__global__ void k_deg(const int* __restrict__ dst, int* __restrict__ deg, int E) {
  int e = blockIdx.x * 256 + threadIdx.x;
  if (e < E) atomicAdd(&deg[dst[e]], 1);
}
__global__ void k_scan1(const int* __restrict__ in, int* __restrict__ out, int* __restrict__ bsums, int n) {
  __shared__ int sh[256];
  int t = threadIdx.x, i = blockIdx.x * 256 + t;
  int v = (i < n) ? in[i] : 0;
  sh[t] = v; __syncthreads();
  for (int o = 1; o < 256; o <<= 1) {
    int add = (t >= o) ? sh[t - o] : 0;
    __syncthreads();
    sh[t] += add;
    __syncthreads();
  }
  if (i < n) out[i] = sh[t] - v;
  if (t == 255) bsums[blockIdx.x] = sh[255];
}
// scan of bsums (done redundantly per block) + offset apply + cursor copy
__global__ void k_scan23(int* offs, int* cur, const int* __restrict__ bsums,
                         int nb, int n, int etot) {
  __shared__ int sh[256];
  int t = threadIdx.x;
  int v = (t < nb) ? bsums[t] : 0;
  sh[t] = v; __syncthreads();
  for (int o = 1; o < 256; o <<= 1) {
    int add = (t >= o) ? sh[t - o] : 0;
    __syncthreads();
    sh[t] += add;
    __syncthreads();
  }
  int base = sh[blockIdx.x] - bsums[blockIdx.x];   // exclusive prefix of this block
  int i = blockIdx.x * 256 + t;
  if (i < n) {
    int o = offs[i] + base;
    offs[i] = o;
    cur[i] = o;
  }
  if (i == 0) offs[n] = etot;
}
__global__ void k_fill(const int* __restrict__ dst, const int* __restrict__ src,
                       int* __restrict__ cursor, int* __restrict__ csr_src, int E) {
  int e = blockIdx.x * 256 + threadIdx.x;
  if (e >= E) return;
  int pos = atomicAdd(&cursor[dst[e]], 1);
  csr_src[pos] = src[e];
}
// ---- wave-parallel bitonic sort per node (deterministic agg order) ----
__global__ void k_sortw(const int* __restrict__ offs, int* __restrict__ csr, int n) {
  int w = threadIdx.x >> 6, lane = threadIdx.x & 63;
  int v = blockIdx.x * 4 + w;
  if (v >= n) return;
  int s = offs[v], e = offs[v + 1];
  int deg = e - s;
  if (deg <= 1) return;
  if (deg > 64) {
    if (lane == 0) {
      for (int i = s + 1; i < e; ++i) {
        int key = csr[i], j = i - 1;
        while (j >= s && csr[j] > key) { csr[j + 1] = csr[j]; --j; }
        csr[j + 1] = key;
      }
    }
    return;
  }
  int val = (lane < deg) ? csr[s + lane] : 0x7fffffff;
#pragma unroll
  for (int k = 2; k <= 64; k <<= 1) {
    bool dir = (lane & k) == 0;
#pragma unroll
    for (int j = k >> 1; j > 0; j >>= 1) {
      int p = __shfl_xor(val, j, 64);
      bool lower = (lane & j) == 0;
      val = (lower == dir) ? min(val, p) : max(val, p);
    }
  }
  if (lane < deg) csr[s + lane] = val;
}

#define ACC8(V)                                              \
  do {                                                       \
    a0 += bf2f((unsigned short)(V).x);                       \
    a1 += bf2f((unsigned short)((V).x >> 16));               \
    a2 += bf2f((unsigned short)(V).y);                       \
    a3 += bf2f((unsigned short)((V).y >> 16));               \
    a4 += bf2f((unsigned short)(V).z);                       \
    a5 += bf2f((unsigned short)((V).z >> 16));               \
    a6 += bf2f((unsigned short)(V).w);                       \
    a7 += bf2f((unsigned short)((V).w >> 16));               \
  } while (0)

// ---- agg-first: Ab[v] = mean_{u in N(v)} H[u] (L3-BW-bound; verified form) ----
__global__ void k_agg(const unsigned short* __restrict__ H, int Kd,
                      const int* __restrict__ offs, const int* __restrict__ csr,
                      unsigned short* __restrict__ Ab) {
  int w = threadIdx.x >> 6, lane = threadIdx.x & 63;
  int v = blockIdx.x * 4 + w;
  int s = offs[v], e = offs[v + 1];
  float inv = 1.f / fmaxf((float)(e - s), 1.f);
  float a0 = 0.f, a1 = 0.f, a2 = 0.f, a3 = 0.f;
  float a4 = 0.f, a5 = 0.f, a6 = 0.f, a7 = 0.f;
  if (Kd == 256) {
    int half = lane >> 5;
    int li = lane & 31;
    int c8 = li * 8;
    int i = s;
    for (; i + 8 <= e; i += 8) {
      uint4 q0 = *(const uint4*)&H[(size_t)csr[i     + half] * 256 + c8];
      uint4 q1 = *(const uint4*)&H[(size_t)csr[i + 2 + half] * 256 + c8];
      uint4 q2 = *(const uint4*)&H[(size_t)csr[i + 4 + half] * 256 + c8];
      uint4 q3 = *(const uint4*)&H[(size_t)csr[i + 6 + half] * 256 + c8];
      ACC8(q0); ACC8(q1); ACC8(q2); ACC8(q3);
    }
    for (; i + 2 <= e; i += 2) {
      uint4 q0 = *(const uint4*)&H[(size_t)csr[i + half] * 256 + c8];
      ACC8(q0);
    }
    if (i < e && half == 0) {
      uint4 q0 = *(const uint4*)&H[(size_t)csr[i] * 256 + c8];
      ACC8(q0);
    }
    a0 += __shfl_xor(a0, 32, 64); a1 += __shfl_xor(a1, 32, 64);
    a2 += __shfl_xor(a2, 32, 64); a3 += __shfl_xor(a3, 32, 64);
    a4 += __shfl_xor(a4, 32, 64); a5 += __shfl_xor(a5, 32, 64);
    a6 += __shfl_xor(a6, 32, 64); a7 += __shfl_xor(a7, 32, 64);
    if (half == 0) {
      uint4 o;
      o.x = cvt2(a0 * inv, a1 * inv);
      o.y = cvt2(a2 * inv, a3 * inv);
      o.z = cvt2(a4 * inv, a5 * inv);
      o.w = cvt2(a6 * inv, a7 * inv);
      *(uint4*)&Ab[(size_t)v * 256 + c8] = o;
    }
  } else {  // Kd == 128
    int hf = lane >> 4;
    int li = lane & 15;
    int c8 = li * 8;
    int i = s;
    for (; i + 16 <= e; i += 16) {
      uint4 q0 = *(const uint4*)&H[(size_t)csr[i      + hf] * 128 + c8];
      uint4 q1 = *(const uint4*)&H[(size_t)csr[i + 4  + hf] * 128 + c8];
      uint4 q2 = *(const uint4*)&H[(size_t)csr[i + 8  + hf] * 128 + c8];
      uint4 q3 = *(const uint4*)&H[(size_t)csr[i + 12 + hf] * 128 + c8];
      ACC8(q0); ACC8(q1); ACC8(q2); ACC8(q3);
    }
    for (; i + 4 <= e; i += 4) {
      uint4 q0 = *(const uint4*)&H[(size_t)csr[i + hf] * 128 + c8];
      ACC8(q0);
    }
    if (hf < e - i) {
      uint4 q0 = *(const uint4*)&H[(size_t)csr[i + hf] * 128 + c8];
      ACC8(q0);
    }
    a0 += __shfl_xor(a0, 16, 64); a1 += __shfl_xor(a1, 16, 64);
    a2 += __shfl_xor(a2, 16, 64); a3 += __shfl_xor(a3, 16, 64);
    a4 += __shfl_xor(a4, 16, 64); a5 += __shfl_xor(a5, 16, 64);
    a6 += __shfl_xor(a6, 16, 64); a7 += __shfl_xor(a7, 16, 64);
    a0 += __shfl_xor(a0, 32, 64); a1 += __shfl_xor(a1, 32, 64);
    a2 += __shfl_xor(a2, 32, 64); a3 += __shfl_xor(a3, 32, 64);
    a4 += __shfl_xor(a4, 32, 64); a5 += __shfl_xor(a5, 32, 64);
    a6 += __shfl_xor(a6, 32, 64); a7 += __shfl_xor(a7, 32, 64);
    if (lane < 16) {
      uint4 o;
      o.x = cvt2(a0 * inv, a1 * inv);
      o.y = cvt2(a2 * inv, a3 * inv);
      o.z = cvt2(a4 * inv, a5 * inv);
      o.w = cvt2(a6 * inv, a7 * inv);
      *(uint4*)&Ab[(size_t)v * 128 + c8] = o;
    }
  }
}

// ---- concat-K layer GEMM v3 (round-11 verified): 512 thr, 128x256 tile ----
__global__ __launch_bounds__(512) void gemm_cat(
    const unsigned short* __restrict__ A1, const unsigned short* __restrict__ A2, int K,
    const unsigned short* __restrict__ B1h, const unsigned short* __restrict__ B2h,
    const float* __restrict__ bias, int relu, int M, unsigned short* __restrict__ O) {
  __shared__ unsigned short sAh[128 * 40];   // 128 rows x 32-short chunk (pad 40)
  __shared__ unsigned short sBh[256 * 40];   // 256 B-rows x 32-short chunk
  int t = threadIdx.x;                       // 0..511
  int m0 = blockIdx.x * 128;
  int wid = t >> 6, lane = t & 63;
  int wr = (wid >> 2) * 64;                  // 0 / 64
  int wc = (wid & 3) * 64;                   // 0 / 64 / 128 / 192
  int quad = lane >> 4, lrow = lane & 15;

  f32x4 acc[4][4];
  const f32x4 z4 = {0.f, 0.f, 0.f, 0.f};
#pragma unroll
  for (int i = 0; i < 4; ++i)
#pragma unroll
    for (int j = 0; j < 4; ++j) acc[i][j] = z4;

  int sra = t >> 2;
  int c8a = (t & 3) * 8;
  int ar = m0 + sra; if (ar >= M) ar = M - 1;
  int brow0 = t >> 2,         bc0 = (t & 3) * 8;
  int brow1 = 128 + (t >> 2), bc1 = bc0;

  int kc = K >> 5;
  int nsteps = kc * 2;

  uint4 pfA  = *(const uint4*)&A1[(size_t)ar * K + c8a];
  uint4 pfB0 = *(const uint4*)&B1h[(size_t)brow0 * K + bc0];
  uint4 pfB1 = *(const uint4*)&B1h[(size_t)brow1 * K + bc1];

  for (int s2 = 0; s2 < nsteps; ++s2) {
    *(uint4*)&sAh[sra * 40 + c8a] = pfA;
    *(uint4*)&sBh[brow0 * 40 + bc0] = pfB0;
    *(uint4*)&sBh[brow1 * 40 + bc1] = pfB1;
    int s1 = s2 + 1;
    if (s1 < nsteps) {
      const unsigned short* Ap = (s1 >= kc) ? A2 : A1;
      const unsigned short* Bp = (s1 >= kc) ? B2h : B1h;
      int k0 = ((s1 >= kc) ? (s1 - kc) : s1) * 32;
      pfA  = *(const uint4*)&Ap[(size_t)ar * K + k0 + c8a];
      pfB0 = *(const uint4*)&Bp[(size_t)brow0 * K + k0 + bc0];
      pfB1 = *(const uint4*)&Bp[(size_t)brow1 * K + k0 + bc1];
    }
    __syncthreads();
    bf16x8 ah[4], bh[4];
#pragma unroll
    for (int i = 0; i < 4; ++i) {
      ah[i] = *(const bf16x8*)&sAh[(wr + i * 16 + lrow) * 40 + quad * 8];
      bh[i] = *(const bf16x8*)&sBh[(wc + i * 16 + lrow) * 40 + quad * 8];
    }
#pragma unroll
    for (int i = 0; i < 4; ++i)
#pragma unroll
      for (int j = 0; j < 4; ++j)
        acc[i][j] = __builtin_amdgcn_mfma_f32_16x16x32_bf16(ah[i], bh[j], acc[i][j], 0, 0, 0);
    __syncthreads();
  }

#pragma unroll
  for (int j = 0; j < 4; ++j) {
    int gc = wc + j * 16 + lrow;
    float bv = bias[gc];
#pragma unroll
    for (int i = 0; i < 4; ++i) {
#pragma unroll
      for (int rr = 0; rr < 4; ++rr) {
        int gr = m0 + wr + i * 16 + quad * 4 + rr;
        if (gr < M) {
          float v = acc[i][j][rr] + bv;
          if (relu) v = fmaxf(v, 0.f);
          O[(size_t)gr * 256 + gc] = cvt1(v);
        }
      }
    }
  }
}

// ---- fully fused predictor: round-3 LDS-B pad-40 body + zT chunk-XOR swizzle
// (swizzle verified r7/r8; pad-40 sBh verified r3/r10 — the untested combo).
// out = relu(relu((H[s]*H[d])@Wp1+b1)@Wp2+b2).wp3+bp3
__global__ __launch_bounds__(256, 3) void gemm_pred_fused(
    const unsigned short* __restrict__ Hb,
    const int* __restrict__ ps, const int* __restrict__ pd,
    const int* __restrict__ ns, const int* __restrict__ nd,
    int nPos,
    const unsigned short* __restrict__ B1h, const float* __restrict__ bp1c,
    const unsigned short* __restrict__ B2h, const float* __restrict__ bp2c,
    const float* __restrict__ wp3, const float* __restrict__ bp3c,
    void* __restrict__ out, const int* __restrict__ flagp) {
  __shared__ __align__(16) unsigned short zT[64 * 264];
  __shared__ __align__(16) unsigned short sBh[256 * 40];
  int t = threadIdx.x;
  int m0 = blockIdx.x * 64;
  int wid = t >> 6, lane = t & 63;
  int wc = wid * 64;
  int quad = lane >> 4, lrow = lane & 15;

  int sr = t >> 2;            // 0..63: A-row owned by this thread
  int c8 = (t & 3) * 8;       // B-staging column offset
  int cq = t & 3;             // column quarter (64 shorts) for A staging
  int c64 = cq * 64;

  int arow = m0 + sr;
  int s, d;
  if (arow < nPos) { s = ps[arow]; d = pd[arow]; }
  else             { s = ns[arow - nPos]; d = nd[arow - nPos]; }
  const unsigned short* Hs = &Hb[(size_t)s * 256];
  const unsigned short* Hd = &Hb[(size_t)d * 256];

  // ---- stage full 64x256 edge-product tile into zT (chunk-XOR swizzled) ----
#pragma unroll
  for (int u = 0; u < 8; ++u) {
    uint4 hs = *(const uint4*)(Hs + c64 + u * 8);
    uint4 hd = *(const uint4*)(Hd + c64 + u * 8);
    uint4 o;
    o.x = cvt2(bf2f((unsigned short)hs.x) * bf2f((unsigned short)hd.x),
               bf2f((unsigned short)(hs.x >> 16)) * bf2f((unsigned short)(hd.x >> 16)));
    o.y = cvt2(bf2f((unsigned short)hs.y) * bf2f((unsigned short)hd.y),
               bf2f((unsigned short)(hs.y >> 16)) * bf2f((unsigned short)(hd.y >> 16)));
    o.z = cvt2(bf2f((unsigned short)hs.z) * bf2f((unsigned short)hd.z),
               bf2f((unsigned short)(hs.z >> 16)) * bf2f((unsigned short)(hd.z >> 16)));
    o.w = cvt2(bf2f((unsigned short)hs.w) * bf2f((unsigned short)hd.w),
               bf2f((unsigned short)(hs.w >> 16)) * bf2f((unsigned short)(hd.w >> 16)));
    *(uint4*)&zT[sr * 264 + c64 + 8 * (u ^ cq)] = o;   // swz within 64-chunk
  }

  f32x4 acc[4][4];
  const f32x4 z4 = {0.f, 0.f, 0.f, 0.f};
#pragma unroll
  for (int i = 0; i < 4; ++i)
#pragma unroll
    for (int j = 0; j < 4; ++j) acc[i][j] = z4;

  // ---- GEMM1: z1 = eTile @ Wp1t ----
  for (int k0 = 0; k0 < 256; k0 += 32) {
#pragma unroll
    for (int rep = 0; rep < 4; ++rep) {
      int r = sr + rep * 64;
      *(uint4*)&sBh[r * 40 + c8] = *(const uint4*)&B1h[(size_t)r * 256 + k0 + c8];
    }
    __syncthreads();   // also orders eTile writes before first read
    bf16x8 ah[4], bh[4];
#pragma unroll
    for (int i = 0; i < 4; ++i) {
      ah[i] = *(const bf16x8*)&zT[(i * 16 + lrow) * 264 + k0 + 8 * (quad ^ (k0 >> 6))];
      bh[i] = *(const bf16x8*)&sBh[(wc + i * 16 + lrow) * 40 + quad * 8];
    }
#pragma unroll
    for (int i = 0; i < 4; ++i)
#pragma unroll
      for (int j = 0; j < 4; ++j)
        acc[i][j] = __builtin_amdgcn_mfma_f32_16x16x32_bf16(ah[i], bh[j], acc[i][j], 0, 0, 0);
    __syncthreads();
  }

  // ---- overwrite zT with relu(z1 + bp1) in bf16 (paired swizzled u32 stores) ----
#pragma unroll
  for (int j = 0; j < 4; ++j) {
    int gc = wc + j * 16 + lrow;          // this lane's own z1 column
    float bv = bp1c[gc];
#pragma unroll
    for (int i = 0; i < 4; ++i) {
#pragma unroll
      for (int rr = 0; rr < 4; ++rr) {
        int rloc = i * 16 + quad * 4 + rr;
        float v = fmaxf(acc[i][j][rr] + bv, 0.f);
        float vn = __shfl_xor(v, 1, 64);  // neighbor lane = gc^1
        if (!(lrow & 1)) {
          int c2 = gc ^ (wid << 3);       // swz(col): chunk = wid
          *(unsigned int*)&zT[rloc * 264 + c2] = cvt2(v, vn);
        }
      }
    }
  }

#pragma unroll
  for (int i = 0; i < 4; ++i)
#pragma unroll
    for (int j = 0; j < 4; ++j) acc[i][j] = z4;

  // ---- GEMM2: z2 = z1Tile @ Wp2t ----
  for (int k0 = 0; k0 < 256; k0 += 32) {
#pragma unroll
    for (int rep = 0; rep < 4; ++rep) {
      int r = sr + rep * 64;
      *(uint4*)&sBh[r * 40 + c8] = *(const uint4*)&B2h[(size_t)r * 256 + k0 + c8];
    }
    __syncthreads();   // also orders z1 writes before first read
    bf16x8 ah[4], bh[4];
#pragma unroll
    for (int i = 0; i < 4; ++i) {
      ah[i] = *(const bf16x8*)&zT[(i * 16 + lrow) * 264 + k0 + 8 * (quad ^ (k0 >> 6))];
      bh[i] = *(const bf16x8*)&sBh[(wc + i * 16 + lrow) * 40 + quad * 8];
    }
#pragma unroll
    for (int i = 0; i < 4; ++i)
#pragma unroll
      for (int j = 0; j < 4; ++j)
        acc[i][j] = __builtin_amdgcn_mfma_f32_16x16x32_bf16(ah[i], bh[j], acc[i][j], 0, 0, 0);
    __syncthreads();
  }

  // ---- epilogue: relu(z2+bp2) . wp3, cross-wave reduce via LDS (reuse sBh) ----
  float* part = (float*)sBh;   // 64 x 65 floats = 16640 B <= 20480 B
  int cid = wid * 16 + lrow;
#pragma unroll
  for (int i = 0; i < 4; ++i) {
#pragma unroll
    for (int rr = 0; rr < 4; ++rr) {
      int rloc = i * 16 + quad * 4 + rr;
      float sum = 0.f;
#pragma unroll
      for (int j = 0; j < 4; ++j) {
        int gc = wc + j * 16 + lrow;
        float v = fmaxf(acc[i][j][rr] + bp2c[gc], 0.f);
        sum += v * wp3[gc];
      }
      part[rloc * 65 + cid] = sum;
    }
  }
  __syncthreads();
  if (t < 64) {
    int gr = m0 + t;
    float ssum = 0.f;
#pragma unroll
    for (int c = 0; c < 64; ++c) ssum += part[t * 65 + c];
    ssum += bp3c[0];
    if (*flagp) ((float*)out)[gr] = ssum;
    else        ((unsigned short*)out)[gr] = f2bf(ssum);
  }
}

extern "C" void kernel_launch(void* const* d_in, const int* in_sizes, int n_in,
                              void* d_out, int out_size, void* d_ws, size_t ws_size,
                              hipStream_t stream) {
  const int N = 50000, E = 800000, P = 100000, DIN = 128, DH = 256;
  const int M2 = 2 * P;                 // 200000 predictor rows
  const void* x = d_in[0];
  const int* esrc = (const int*)d_in[1];
  const int* edst = (const int*)d_in[2];
  const int* psrc = (const int*)d_in[3];
  const int* pdst = (const int*)d_in[4];
  const int* nsrc = (const int*)d_in[5];
  const int* ndst = (const int*)d_in[6];
  const void* Ws0 = d_in[7];  const void* Wn0 = d_in[8];  const void* b0 = d_in[9];
  const void* Ws1 = d_in[10]; const void* Wn1 = d_in[11]; const void* b1 = d_in[12];
  const void* Ws2 = d_in[13]; const void* Wn2 = d_in[14]; const void* b2 = d_in[15];
  const void* Wp1 = d_in[16]; const void* bp1 = d_in[17];
  const void* Wp2 = d_in[18]; const void* bp2 = d_in[19];
  const void* Wp3 = d_in[20]; const void* bp3 = d_in[21];
  (void)in_sizes; (void)n_in; (void)out_size; (void)ws_size;

  // ---- workspace layout ----
  const size_t NH = (size_t)N * DH;               // 12.8M elems
  unsigned short* planeA = (unsigned short*)d_ws; // [N,256] bf16 (holds Xb for L0)
  unsigned short* Xb = planeA;
  char* reg1 = (char*)d_ws + NH * 2;              // 102.4 MB region
  unsigned short* AggB  = (unsigned short*)reg1;          // [N,256] bf16 agg buffer
  unsigned short* planeB = (unsigned short*)(reg1 + NH * 4);  // [N,256] bf16
  float* P0 = (float*)(reg1 + (size_t)M2 * 256 * 2);      // (legacy, unused)
  float* P1 = P0 + M2;
  unsigned short* W16 = (unsigned short*)(P1 + M2);
  unsigned short* ws0h = W16;                     // K=128: 32768 each
  unsigned short* wn0h = ws0h + 32768;
  unsigned short* ws1h = wn0h + 32768;            // K=256: 65536 each
  unsigned short* wn1h = ws1h + 65536;
  unsigned short* ws2h = wn1h + 65536;
  unsigned short* wn2h = ws2h + 65536;
  unsigned short* wp1h = wn2h + 65536;
  unsigned short* wp2h = wp1h + 65536;
  float* FB = (float*)(wp2h + 65536);
  float* b0f  = FB;
  float* b1f  = b0f + 256;
  float* b2f  = b1f + 256;
  float* bp1f = b2f + 256;
  float* bp2f = bp1f + 256;
  float* wp3f = bp2f + 256;
  float* bp3f = wp3f + 256;
  int* deg   = (int*)(bp3f + 4);
  int* offs  = deg + N;
  int* cur   = offs + (N + 1);
  int* bsums = cur + N;
  int* csr   = bsums + 256;
  int* flagp = csr + E;

  // ---- dtype detection ----
  k_detect<<<1, 256, 0, stream>>>((const unsigned short*)x, 8192, flagp);

  // ---- weight transposes + small cvts, one dispatch ----
  k_wh8<<<1799, 256, 0, stream>>>(Ws0, Wn0, Ws1, Wn1, Ws2, Wn2, Wp1, Wp2,
                                  ws0h, wn0h, ws1h, wn1h, ws2h, wn2h, wp1h, wp2h,
                                  b0, b1, b2, bp1, bp2, Wp3, bp3,
                                  b0f, b1f, b2f, bp1f, bp2f, wp3f, bp3f,
                                  flagp);

  // ---- CSR build (deterministic) ----
  int nb = CDIV(N, 256);
  k_zero_i32<<<nb, 256, 0, stream>>>(deg, N);
  k_deg<<<CDIV(E, 256), 256, 0, stream>>>(edst, deg, E);
  k_scan1<<<nb, 256, 0, stream>>>(deg, offs, bsums, N);
  k_scan23<<<nb, 256, 0, stream>>>(offs, cur, bsums, nb, N, E);
  k_fill<<<CDIV(E, 256), 256, 0, stream>>>(edst, esrc, cur, csr, E);
  k_sortw<<<CDIV(N, 4), 256, 0, stream>>>(offs, csr, N);

  const int G_C = CDIV(N, 128);         // 391 blocks per layer GEMM (512 thr)

  // ---- Layer 0: agg-first over x, then fused concat GEMM -> planeB ----
  k_xbf16<<<CDIV(N * DIN, 256), 256, 0, stream>>>(x, Xb, N * DIN, flagp);
  k_agg<<<N / 4, 256, 0, stream>>>(Xb, DIN, offs, csr, AggB);
  gemm_cat<<<G_C, 512, 0, stream>>>(Xb, AggB, DIN, ws0h, wn0h, b0f, 1, N, planeB);

  // ---- Layer 1: planeB -> planeA ----
  k_agg<<<N / 4, 256, 0, stream>>>(planeB, DH, offs, csr, AggB);
  gemm_cat<<<G_C, 512, 0, stream>>>(planeB, AggB, DH, ws1h, wn1h, b1f, 1, N, planeA);

  // ---- Layer 2 (no relu): planeA -> planeB ----
  k_agg<<<N / 4, 256, 0, stream>>>(planeA, DH, offs, csr, AggB);
  gemm_cat<<<G_C, 512, 0, stream>>>(planeA, AggB, DH, ws2h, wn2h, b2f, 0, N, planeB);

  // ---- Predictor: one fully fused pass over all 200000 pairs ----
  gemm_pred_fused<<<M2 / 64, 256, 0, stream>>>(planeB, psrc, pdst, nsrc, ndst, P,
                                               wp1h, bp1f, wp2h, bp2f, wp3f, bp3f,
                                               d_out, flagp);
}

// Round 14
// 570.834 us; speedup vs baseline: 1.0310x; 1.0310x over previous
//
#include <hip/hip_runtime.h>
#include <hip/hip_bf16.h>

#define CDIV(a, b) (((a) + (b) - 1) / (b))

typedef __attribute__((ext_vector_type(8))) __bf16 bf16x8;
typedef __attribute__((ext_vector_type(2))) __bf16 bf16x2;
typedef __attribute__((ext_vector_type(4))) float f32x4;

__device__ __forceinline__ float bf2f(unsigned short u) {
  union { unsigned int i; float f; } c; c.i = ((unsigned int)u) << 16; return c.f;
}
__device__ __forceinline__ unsigned short f2bf(float f) {
  union { float f; unsigned int i; } c; c.f = f;
  unsigned int r = c.i + 0x7fffu + ((c.i >> 16) & 1u);
  return (unsigned short)(r >> 16);
}
// two floats -> packed bf16x2 in one u32 (v_cvt_pk_bf16_f32)
__device__ __forceinline__ unsigned int cvt2(float a, float b) {
  bf16x2 v; v[0] = (__bf16)a; v[1] = (__bf16)b;
  union { bf16x2 v; unsigned int u; } c; c.v = v; return c.u;
}
__device__ __forceinline__ unsigned short cvt1(float a) {
  __bf16 b = (__bf16)a;
  union { __bf16 b; unsigned short u; } c; c.b = b; return c.u;
}

// ---- dtype detector: flag=1 if fp32 storage, 0 if bf16 storage ----
__global__ void k_detect(const unsigned short* __restrict__ xq, int nsamp, int* __restrict__ flagp) {
  __shared__ float sm[256];
  int t = threadIdx.x;
  float mx = 0.f;
  for (int i = t; i < nsamp; i += 256) {
    float v = bf2f(xq[i]);
    if (!(v == v)) v = 1e30f;
    mx = fmaxf(mx, fabsf(v));
  }
  sm[t] = mx; __syncthreads();
  for (int o = 128; o > 0; o >>= 1) {
    if (t < o) sm[t] = fmaxf(sm[t], sm[t + o]);
    __syncthreads();
  }
  if (t == 0) *flagp = (sm[0] > 1e6f) ? 1 : 0;
}

// ---- 8 weight transposes + 7 small cvts in ONE dispatch ----
// grid = 128 + 128 + 6*256 + 7 = 1799 blocks of 256 threads.
__global__ void k_wh8(const void* s0, const void* s1, const void* s2, const void* s3,
                      const void* s4, const void* s5, const void* s6, const void* s7,
                      unsigned short* d0, unsigned short* d1, unsigned short* d2,
                      unsigned short* d3, unsigned short* d4, unsigned short* d5,
                      unsigned short* d6, unsigned short* d7,
                      const void* p0, const void* p1, const void* p2, const void* p3,
                      const void* p4, const void* p5, const void* p6,
                      float* f0, float* f1, float* f2, float* f3,
                      float* f4, float* f5, float* f6,
                      const int* __restrict__ flagp) {
  int b = blockIdx.x, t = threadIdx.x;
  if (b >= 1792) {  // cvt tail
    int c = b - 1792;
    const void* s = 0; float* d = 0; int n = 256;
    switch (c) {
      case 0: s = p0; d = f0; break;
      case 1: s = p1; d = f1; break;
      case 2: s = p2; d = f2; break;
      case 3: s = p3; d = f3; break;
      case 4: s = p4; d = f4; break;
      case 5: s = p5; d = f5; break;
      default: s = p6; d = f6; n = 1; break;
    }
    if (t < n) d[t] = (*flagp) ? ((const float*)s)[t] : bf2f(((const unsigned short*)s)[t]);
    return;
  }
  const void* W; unsigned short* Bt; int K; int base;
  if (b < 128)       { W = s0; Bt = d0; K = 128; base = 0; }
  else if (b < 256)  { W = s1; Bt = d1; K = 128; base = 128; }
  else {
    int r = (b - 256) >> 8;       // 0..5
    base = 256 + r * 256; K = 256;
    switch (r) {
      case 0:  W = s2; Bt = d2; break;
      case 1:  W = s3; Bt = d3; break;
      case 2:  W = s4; Bt = d4; break;
      case 3:  W = s5; Bt = d5; break;
      case 4:  W = s6; Bt = d6; break;
      default: W = s7; Bt = d7; break;
    }
  }
  int i = (b - base) * 256 + t;   // < K*256 by grid construction
  int k = i >> 8, n = i & 255;
  float v = (*flagp) ? ((const float*)W)[i] : bf2f(((const unsigned short*)W)[i]);
  Bt[(size_t)n * K + k] = f2bf(v);
}

// ---- x -> bf16 plane ----
__global__ void k_xbf16(const void* __restrict__ x, unsigned short* __restrict__ Xb, int n,
                        const int* __restrict__ flagp) {
  int i = blockIdx.x * 256 + threadIdx.x;
  if (i >= n) return;
  float v = (*flagp) ? ((const float*)x)[i] : bf2f(((const unsigned short*)x)[i]);
  Xb[i] = f2bf(v);
}

__global__ void k_zero_i32(int* p, int n) {
  int i = blockIdx.x * 256 + threadIdx.x;
  if (i < n) p[i] = 0;
}

// ---------------- CSR build ----------------
__global__ void k_deg(const int* __restrict__ dst, int* __restrict__ deg, int E) {
  int e = blockIdx.x * 256 + threadIdx.x;
  if (e < E) atomicAdd(&deg[dst[e]], 1);
}
__global__ void k_scan1(const int* __restrict__ in, int* __restrict__ out, int* __restrict__ bsums, int n) {
  __shared__ int sh[256];
  int t = threadIdx.x, i = blockIdx.x * 256 + t;
  int v = (i < n) ? in[i] : 0;
  sh[t] = v; __syncthreads();
  for (int o = 1; o < 256; o <<= 1) {
    int add = (t >= o) ? sh[t - o] : 0;
    __syncthreads();
    sh[t] += add;
    __syncthreads();
  }
  if (i < n) out[i] = sh[t] - v;
  if (t == 255) bsums[blockIdx.x] = sh[255];
}
// scan of bsums (done redundantly per block) + offset apply + cursor copy
__global__ void k_scan23(int* offs, int* cur, const int* __restrict__ bsums,
                         int nb, int n, int etot) {
  __shared__ int sh[256];
  int t = threadIdx.x;
  int v = (t < nb) ? bsums[t] : 0;
  sh[t] = v; __syncthreads();
  for (int o = 1; o < 256; o <<= 1) {
    int add = (t >= o) ? sh[t - o] : 0;
    __syncthreads();
    sh[t] += add;
    __syncthreads();
  }
  int base = sh[blockIdx.x] - bsums[blockIdx.x];   // exclusive prefix of this block
  int i = blockIdx.x * 256 + t;
  if (i < n) {
    int o = offs[i] + base;
    offs[i] = o;
    cur[i] = o;
  }
  if (i == 0) offs[n] = etot;
}
__global__ void k_fill(const int* __restrict__ dst, const int* __restrict__ src,
                       int* __restrict__ cursor, int* __restrict__ csr_src, int E) {
  int e = blockIdx.x * 256 + threadIdx.x;
  if (e >= E) return;
  int pos = atomicAdd(&cursor[dst[e]], 1);
  csr_src[pos] = src[e];
}
// ---- wave-parallel bitonic sort per node (deterministic agg order) ----
__global__ void k_sortw(const int* __restrict__ offs, int* __restrict__ csr, int n) {
  int w = threadIdx.x >> 6, lane = threadIdx.x & 63;
  int v = blockIdx.x * 4 + w;
  if (v >= n) return;
  int s = offs[v], e = offs[v + 1];
  int deg = e - s;
  if (deg <= 1) return;
  if (deg > 64) {
    if (lane == 0) {
      for (int i = s + 1; i < e; ++i) {
        int key = csr[i], j = i - 1;
        while (j >= s && csr[j] > key) { csr[j + 1] = csr[j]; --j; }
        csr[j + 1] = key;
      }
    }
    return;
  }
  int val = (lane < deg) ? csr[s + lane] : 0x7fffffff;
#pragma unroll
  for (int k = 2; k <= 64; k <<= 1) {
    bool dir = (lane & k) == 0;
#pragma unroll
    for (int j = k >> 1; j > 0; j >>= 1) {
      int p = __shfl_xor(val, j, 64);
      bool lower = (lane & j) == 0;
      val = (lower == dir) ? min(val, p) : max(val, p);
    }
  }
  if (lane < deg) csr[s + lane] = val;
}

#define ACC8(V)                                              \
  do {                                                       \
    a0 += bf2f((unsigned short)(V).x);                       \
    a1 += bf2f((unsigned short)((V).x >> 16));               \
    a2 += bf2f((unsigned short)(V).y);                       \
    a3 += bf2f((unsigned short)((V).y >> 16));               \
    a4 += bf2f((unsigned short)(V).z);                       \
    a5 += bf2f((unsigned short)((V).z >> 16));               \
    a6 += bf2f((unsigned short)(V).w);                       \
    a7 += bf2f((unsigned short)((V).w >> 16));               \
  } while (0)

// ---- agg-first: Ab[v] = mean_{u in N(v)} H[u] (L3-BW-bound; verified form) ----
__global__ void k_agg(const unsigned short* __restrict__ H, int Kd,
                      const int* __restrict__ offs, const int* __restrict__ csr,
                      unsigned short* __restrict__ Ab) {
  int w = threadIdx.x >> 6, lane = threadIdx.x & 63;
  int v = blockIdx.x * 4 + w;
  int s = offs[v], e = offs[v + 1];
  float inv = 1.f / fmaxf((float)(e - s), 1.f);
  float a0 = 0.f, a1 = 0.f, a2 = 0.f, a3 = 0.f;
  float a4 = 0.f, a5 = 0.f, a6 = 0.f, a7 = 0.f;
  if (Kd == 256) {
    int half = lane >> 5;
    int li = lane & 31;
    int c8 = li * 8;
    int i = s;
    for (; i + 8 <= e; i += 8) {
      uint4 q0 = *(const uint4*)&H[(size_t)csr[i     + half] * 256 + c8];
      uint4 q1 = *(const uint4*)&H[(size_t)csr[i + 2 + half] * 256 + c8];
      uint4 q2 = *(const uint4*)&H[(size_t)csr[i + 4 + half] * 256 + c8];
      uint4 q3 = *(const uint4*)&H[(size_t)csr[i + 6 + half] * 256 + c8];
      ACC8(q0); ACC8(q1); ACC8(q2); ACC8(q3);
    }
    for (; i + 2 <= e; i += 2) {
      uint4 q0 = *(const uint4*)&H[(size_t)csr[i + half] * 256 + c8];
      ACC8(q0);
    }
    if (i < e && half == 0) {
      uint4 q0 = *(const uint4*)&H[(size_t)csr[i] * 256 + c8];
      ACC8(q0);
    }
    a0 += __shfl_xor(a0, 32, 64); a1 += __shfl_xor(a1, 32, 64);
    a2 += __shfl_xor(a2, 32, 64); a3 += __shfl_xor(a3, 32, 64);
    a4 += __shfl_xor(a4, 32, 64); a5 += __shfl_xor(a5, 32, 64);
    a6 += __shfl_xor(a6, 32, 64); a7 += __shfl_xor(a7, 32, 64);
    if (half == 0) {
      uint4 o;
      o.x = cvt2(a0 * inv, a1 * inv);
      o.y = cvt2(a2 * inv, a3 * inv);
      o.z = cvt2(a4 * inv, a5 * inv);
      o.w = cvt2(a6 * inv, a7 * inv);
      *(uint4*)&Ab[(size_t)v * 256 + c8] = o;
    }
  } else {  // Kd == 128
    int hf = lane >> 4;
    int li = lane & 15;
    int c8 = li * 8;
    int i = s;
    for (; i + 16 <= e; i += 16) {
      uint4 q0 = *(const uint4*)&H[(size_t)csr[i      + hf] * 128 + c8];
      uint4 q1 = *(const uint4*)&H[(size_t)csr[i + 4  + hf] * 128 + c8];
      uint4 q2 = *(const uint4*)&H[(size_t)csr[i + 8  + hf] * 128 + c8];
      uint4 q3 = *(const uint4*)&H[(size_t)csr[i + 12 + hf] * 128 + c8];
      ACC8(q0); ACC8(q1); ACC8(q2); ACC8(q3);
    }
    for (; i + 4 <= e; i += 4) {
      uint4 q0 = *(const uint4*)&H[(size_t)csr[i + hf] * 128 + c8];
      ACC8(q0);
    }
    if (hf < e - i) {
      uint4 q0 = *(const uint4*)&H[(size_t)csr[i + hf] * 128 + c8];
      ACC8(q0);
    }
    a0 += __shfl_xor(a0, 16, 64); a1 += __shfl_xor(a1, 16, 64);
    a2 += __shfl_xor(a2, 16, 64); a3 += __shfl_xor(a3, 16, 64);
    a4 += __shfl_xor(a4, 16, 64); a5 += __shfl_xor(a5, 16, 64);
    a6 += __shfl_xor(a6, 16, 64); a7 += __shfl_xor(a7, 16, 64);
    a0 += __shfl_xor(a0, 32, 64); a1 += __shfl_xor(a1, 32, 64);
    a2 += __shfl_xor(a2, 32, 64); a3 += __shfl_xor(a3, 32, 64);
    a4 += __shfl_xor(a4, 32, 64); a5 += __shfl_xor(a5, 32, 64);
    a6 += __shfl_xor(a6, 32, 64); a7 += __shfl_xor(a7, 32, 64);
    if (lane < 16) {
      uint4 o;
      o.x = cvt2(a0 * inv, a1 * inv);
      o.y = cvt2(a2 * inv, a3 * inv);
      o.z = cvt2(a4 * inv, a5 * inv);
      o.w = cvt2(a6 * inv, a7 * inv);
      *(uint4*)&Ab[(size_t)v * 128 + c8] = o;
    }
  }
}

// ---- concat-K layer GEMM v3 (round-11 verified): 512 thr, 128x256 tile ----
__global__ __launch_bounds__(512) void gemm_cat(
    const unsigned short* __restrict__ A1, const unsigned short* __restrict__ A2, int K,
    const unsigned short* __restrict__ B1h, const unsigned short* __restrict__ B2h,
    const float* __restrict__ bias, int relu, int M, unsigned short* __restrict__ O) {
  __shared__ unsigned short sAh[128 * 40];   // 128 rows x 32-short chunk (pad 40)
  __shared__ unsigned short sBh[256 * 40];   // 256 B-rows x 32-short chunk
  int t = threadIdx.x;                       // 0..511
  int m0 = blockIdx.x * 128;
  int wid = t >> 6, lane = t & 63;
  int wr = (wid >> 2) * 64;                  // 0 / 64
  int wc = (wid & 3) * 64;                   // 0 / 64 / 128 / 192
  int quad = lane >> 4, lrow = lane & 15;

  f32x4 acc[4][4];
  const f32x4 z4 = {0.f, 0.f, 0.f, 0.f};
#pragma unroll
  for (int i = 0; i < 4; ++i)
#pragma unroll
    for (int j = 0; j < 4; ++j) acc[i][j] = z4;

  int sra = t >> 2;
  int c8a = (t & 3) * 8;
  int ar = m0 + sra; if (ar >= M) ar = M - 1;
  int brow0 = t >> 2,         bc0 = (t & 3) * 8;
  int brow1 = 128 + (t >> 2), bc1 = bc0;

  int kc = K >> 5;
  int nsteps = kc * 2;

  uint4 pfA  = *(const uint4*)&A1[(size_t)ar * K + c8a];
  uint4 pfB0 = *(const uint4*)&B1h[(size_t)brow0 * K + bc0];
  uint4 pfB1 = *(const uint4*)&B1h[(size_t)brow1 * K + bc1];

  for (int s2 = 0; s2 < nsteps; ++s2) {
    *(uint4*)&sAh[sra * 40 + c8a] = pfA;
    *(uint4*)&sBh[brow0 * 40 + bc0] = pfB0;
    *(uint4*)&sBh[brow1 * 40 + bc1] = pfB1;
    int s1 = s2 + 1;
    if (s1 < nsteps) {
      const unsigned short* Ap = (s1 >= kc) ? A2 : A1;
      const unsigned short* Bp = (s1 >= kc) ? B2h : B1h;
      int k0 = ((s1 >= kc) ? (s1 - kc) : s1) * 32;
      pfA  = *(const uint4*)&Ap[(size_t)ar * K + k0 + c8a];
      pfB0 = *(const uint4*)&Bp[(size_t)brow0 * K + k0 + bc0];
      pfB1 = *(const uint4*)&Bp[(size_t)brow1 * K + k0 + bc1];
    }
    __syncthreads();
    bf16x8 ah[4], bh[4];
#pragma unroll
    for (int i = 0; i < 4; ++i) {
      ah[i] = *(const bf16x8*)&sAh[(wr + i * 16 + lrow) * 40 + quad * 8];
      bh[i] = *(const bf16x8*)&sBh[(wc + i * 16 + lrow) * 40 + quad * 8];
    }
#pragma unroll
    for (int i = 0; i < 4; ++i)
#pragma unroll
      for (int j = 0; j < 4; ++j)
        acc[i][j] = __builtin_amdgcn_mfma_f32_16x16x32_bf16(ah[i], bh[j], acc[i][j], 0, 0, 0);
    __syncthreads();
  }

#pragma unroll
  for (int j = 0; j < 4; ++j) {
    int gc = wc + j * 16 + lrow;
    float bv = bias[gc];
#pragma unroll
    for (int i = 0; i < 4; ++i) {
#pragma unroll
      for (int rr = 0; rr < 4; ++rr) {
        int gr = m0 + wr + i * 16 + quad * 4 + rr;
        if (gr < M) {
          float v = acc[i][j][rr] + bv;
          if (relu) v = fmaxf(v, 0.f);
          O[(size_t)gr * 256 + gc] = cvt1(v);
        }
      }
    }
  }
}

// ---- fully fused predictor (round-3/10/11 verified 130us body — optimum of
// six structural variants; conflicts proven non-binding) ----
// out = relu(relu((H[s]*H[d])@Wp1+b1)@Wp2+b2).wp3+bp3
__global__ __launch_bounds__(256, 3) void gemm_pred_fused(
    const unsigned short* __restrict__ Hb,
    const int* __restrict__ ps, const int* __restrict__ pd,
    const int* __restrict__ ns, const int* __restrict__ nd,
    int nPos,
    const unsigned short* __restrict__ B1h, const float* __restrict__ bp1c,
    const unsigned short* __restrict__ B2h, const float* __restrict__ bp2c,
    const float* __restrict__ wp3, const float* __restrict__ bp3c,
    void* __restrict__ out, const int* __restrict__ flagp) {
  __shared__ __align__(16) unsigned short zT[64 * 264];
  __shared__ __align__(16) unsigned short sBh[256 * 40];
  int t = threadIdx.x;
  int m0 = blockIdx.x * 64;
  int wid = t >> 6, lane = t & 63;
  int wc = wid * 64;
  int quad = lane >> 4, lrow = lane & 15;

  int sr = t >> 2;            // 0..63: A-row owned by this thread
  int c8 = (t & 3) * 8;       // B-staging column offset
  int c64 = (t & 3) * 64;     // A-staging column block

  int arow = m0 + sr;
  int s, d;
  if (arow < nPos) { s = ps[arow]; d = pd[arow]; }
  else             { s = ns[arow - nPos]; d = nd[arow - nPos]; }
  const unsigned short* Hs = &Hb[(size_t)s * 256];
  const unsigned short* Hd = &Hb[(size_t)d * 256];

  // ---- stage full 64x256 edge-product tile into zT (gather ONCE) ----
#pragma unroll
  for (int u = 0; u < 8; ++u) {
    uint4 hs = *(const uint4*)(Hs + c64 + u * 8);
    uint4 hd = *(const uint4*)(Hd + c64 + u * 8);
    uint4 o;
    o.x = cvt2(bf2f((unsigned short)hs.x) * bf2f((unsigned short)hd.x),
               bf2f((unsigned short)(hs.x >> 16)) * bf2f((unsigned short)(hd.x >> 16)));
    o.y = cvt2(bf2f((unsigned short)hs.y) * bf2f((unsigned short)hd.y),
               bf2f((unsigned short)(hs.y >> 16)) * bf2f((unsigned short)(hd.y >> 16)));
    o.z = cvt2(bf2f((unsigned short)hs.z) * bf2f((unsigned short)hd.z),
               bf2f((unsigned short)(hs.z >> 16)) * bf2f((unsigned short)(hd.z >> 16)));
    o.w = cvt2(bf2f((unsigned short)hs.w) * bf2f((unsigned short)hd.w),
               bf2f((unsigned short)(hs.w >> 16)) * bf2f((unsigned short)(hd.w >> 16)));
    *(uint4*)&zT[sr * 264 + c64 + u * 8] = o;
  }

  f32x4 acc[4][4];
  const f32x4 z4 = {0.f, 0.f, 0.f, 0.f};
#pragma unroll
  for (int i = 0; i < 4; ++i)
#pragma unroll
    for (int j = 0; j < 4; ++j) acc[i][j] = z4;

  // ---- GEMM1: z1 = eTile @ Wp1t ----
  for (int k0 = 0; k0 < 256; k0 += 32) {
#pragma unroll
    for (int rep = 0; rep < 4; ++rep) {
      int r = sr + rep * 64;
      *(uint4*)&sBh[r * 40 + c8] = *(const uint4*)&B1h[(size_t)r * 256 + k0 + c8];
    }
    __syncthreads();   // also orders eTile writes before first read
    bf16x8 ah[4], bh[4];
#pragma unroll
    for (int i = 0; i < 4; ++i) {
      ah[i] = *(const bf16x8*)&zT[(i * 16 + lrow) * 264 + k0 + quad * 8];
      bh[i] = *(const bf16x8*)&sBh[(wc + i * 16 + lrow) * 40 + quad * 8];
    }
#pragma unroll
    for (int i = 0; i < 4; ++i)
#pragma unroll
      for (int j = 0; j < 4; ++j)
        acc[i][j] = __builtin_amdgcn_mfma_f32_16x16x32_bf16(ah[i], bh[j], acc[i][j], 0, 0, 0);
    __syncthreads();
  }

  // ---- overwrite zT with relu(z1 + bp1) in bf16 ----
#pragma unroll
  for (int j = 0; j < 4; ++j) {
    int gc = wc + j * 16 + lrow;
    float bv = bp1c[gc];
#pragma unroll
    for (int i = 0; i < 4; ++i) {
#pragma unroll
      for (int rr = 0; rr < 4; ++rr) {
        int rloc = i * 16 + quad * 4 + rr;
        float v = fmaxf(acc[i][j][rr] + bv, 0.f);
        zT[rloc * 264 + gc] = cvt1(v);
      }
    }
  }

#pragma unroll
  for (int i = 0; i < 4; ++i)
#pragma unroll
    for (int j = 0; j < 4; ++j) acc[i][j] = z4;

  // ---- GEMM2: z2 = z1Tile @ Wp2t ----
  for (int k0 = 0; k0 < 256; k0 += 32) {
#pragma unroll
    for (int rep = 0; rep < 4; ++rep) {
      int r = sr + rep * 64;
      *(uint4*)&sBh[r * 40 + c8] = *(const uint4*)&B2h[(size_t)r * 256 + k0 + c8];
    }
    __syncthreads();   // also orders z1 writes before first read
    bf16x8 ah[4], bh[4];
#pragma unroll
    for (int i = 0; i < 4; ++i) {
      ah[i] = *(const bf16x8*)&zT[(i * 16 + lrow) * 264 + k0 + quad * 8];
      bh[i] = *(const bf16x8*)&sBh[(wc + i * 16 + lrow) * 40 + quad * 8];
    }
#pragma unroll
    for (int i = 0; i < 4; ++i)
#pragma unroll
      for (int j = 0; j < 4; ++j)
        acc[i][j] = __builtin_amdgcn_mfma_f32_16x16x32_bf16(ah[i], bh[j], acc[i][j], 0, 0, 0);
    __syncthreads();
  }

  // ---- epilogue: relu(z2+bp2) . wp3, cross-wave reduce via LDS (reuse sBh) ----
  float* part = (float*)sBh;   // 64 x 65 floats = 16640 B <= 20480 B
  int cid = wid * 16 + lrow;
#pragma unroll
  for (int i = 0; i < 4; ++i) {
#pragma unroll
    for (int rr = 0; rr < 4; ++rr) {
      int rloc = i * 16 + quad * 4 + rr;
      float sum = 0.f;
#pragma unroll
      for (int j = 0; j < 4; ++j) {
        int gc = wc + j * 16 + lrow;
        float v = fmaxf(acc[i][j][rr] + bp2c[gc], 0.f);
        sum += v * wp3[gc];
      }
      part[rloc * 65 + cid] = sum;
    }
  }
  __syncthreads();
  if (t < 64) {
    int gr = m0 + t;
    float ssum = 0.f;
#pragma unroll
    for (int c = 0; c < 64; ++c) ssum += part[t * 65 + c];
    ssum += bp3c[0];
    if (*flagp) ((float*)out)[gr] = ssum;
    else        ((unsigned short*)out)[gr] = f2bf(ssum);
  }
}

extern "C" void kernel_launch(void* const* d_in, const int* in_sizes, int n_in,
                              void* d_out, int out_size, void* d_ws, size_t ws_size,
                              hipStream_t stream) {
  const int N = 50000, E = 800000, P = 100000, DIN = 128, DH = 256;
  const int M2 = 2 * P;                 // 200000 predictor rows
  const void* x = d_in[0];
  const int* esrc = (const int*)d_in[1];
  const int* edst = (const int*)d_in[2];
  const int* psrc = (const int*)d_in[3];
  const int* pdst = (const int*)d_in[4];
  const int* nsrc = (const int*)d_in[5];
  const int* ndst = (const int*)d_in[6];
  const void* Ws0 = d_in[7];  const void* Wn0 = d_in[8];  const void* b0 = d_in[9];
  const void* Ws1 = d_in[10]; const void* Wn1 = d_in[11]; const void* b1 = d_in[12];
  const void* Ws2 = d_in[13]; const void* Wn2 = d_in[14]; const void* b2 = d_in[15];
  const void* Wp1 = d_in[16]; const void* bp1 = d_in[17];
  const void* Wp2 = d_in[18]; const void* bp2 = d_in[19];
  const void* Wp3 = d_in[20]; const void* bp3 = d_in[21];
  (void)in_sizes; (void)n_in; (void)out_size; (void)ws_size;

  // ---- workspace layout ----
  const size_t NH = (size_t)N * DH;               // 12.8M elems
  unsigned short* planeA = (unsigned short*)d_ws; // [N,256] bf16 (holds Xb for L0)
  unsigned short* Xb = planeA;
  char* reg1 = (char*)d_ws + NH * 2;              // 102.4 MB region
  unsigned short* AggB  = (unsigned short*)reg1;          // [N,256] bf16 agg buffer
  unsigned short* planeB = (unsigned short*)(reg1 + NH * 4);  // [N,256] bf16
  float* P0 = (float*)(reg1 + (size_t)M2 * 256 * 2);      // (legacy, unused)
  float* P1 = P0 + M2;
  unsigned short* W16 = (unsigned short*)(P1 + M2);
  unsigned short* ws0h = W16;                     // K=128: 32768 each
  unsigned short* wn0h = ws0h + 32768;
  unsigned short* ws1h = wn0h + 32768;            // K=256: 65536 each
  unsigned short* wn1h = ws1h + 65536;
  unsigned short* ws2h = wn1h + 65536;
  unsigned short* wn2h = ws2h + 65536;
  unsigned short* wp1h = wn2h + 65536;
  unsigned short* wp2h = wp1h + 65536;
  float* FB = (float*)(wp2h + 65536);
  float* b0f  = FB;
  float* b1f  = b0f + 256;
  float* b2f  = b1f + 256;
  float* bp1f = b2f + 256;
  float* bp2f = bp1f + 256;
  float* wp3f = bp2f + 256;
  float* bp3f = wp3f + 256;
  int* deg   = (int*)(bp3f + 4);
  int* offs  = deg + N;
  int* cur   = offs + (N + 1);
  int* bsums = cur + N;
  int* csr   = bsums + 256;
  int* flagp = csr + E;

  // ---- dtype detection ----
  k_detect<<<1, 256, 0, stream>>>((const unsigned short*)x, 8192, flagp);

  // ---- weight transposes + small cvts, one dispatch ----
  k_wh8<<<1799, 256, 0, stream>>>(Ws0, Wn0, Ws1, Wn1, Ws2, Wn2, Wp1, Wp2,
                                  ws0h, wn0h, ws1h, wn1h, ws2h, wn2h, wp1h, wp2h,
                                  b0, b1, b2, bp1, bp2, Wp3, bp3,
                                  b0f, b1f, b2f, bp1f, bp2f, wp3f, bp3f,
                                  flagp);

  // ---- CSR build (deterministic) ----
  int nb = CDIV(N, 256);
  k_zero_i32<<<nb, 256, 0, stream>>>(deg, N);
  k_deg<<<CDIV(E, 256), 256, 0, stream>>>(edst, deg, E);
  k_scan1<<<nb, 256, 0, stream>>>(deg, offs, bsums, N);
  k_scan23<<<nb, 256, 0, stream>>>(offs, cur, bsums, nb, N, E);
  k_fill<<<CDIV(E, 256), 256, 0, stream>>>(edst, esrc, cur, csr, E);
  k_sortw<<<CDIV(N, 4), 256, 0, stream>>>(offs, csr, N);

  const int G_C = CDIV(N, 128);         // 391 blocks per layer GEMM (512 thr)

  // ---- Layer 0: agg-first over x, then fused concat GEMM -> planeB ----
  k_xbf16<<<CDIV(N * DIN, 256), 256, 0, stream>>>(x, Xb, N * DIN, flagp);
  k_agg<<<N / 4, 256, 0, stream>>>(Xb, DIN, offs, csr, AggB);
  gemm_cat<<<G_C, 512, 0, stream>>>(Xb, AggB, DIN, ws0h, wn0h, b0f, 1, N, planeB);

  // ---- Layer 1: planeB -> planeA ----
  k_agg<<<N / 4, 256, 0, stream>>>(planeB, DH, offs, csr, AggB);
  gemm_cat<<<G_C, 512, 0, stream>>>(planeB, AggB, DH, ws1h, wn1h, b1f, 1, N, planeA);

  // ---- Layer 2 (no relu): planeA -> planeB ----
  k_agg<<<N / 4, 256, 0, stream>>>(planeA, DH, offs, csr, AggB);
  gemm_cat<<<G_C, 512, 0, stream>>>(planeA, AggB, DH, ws2h, wn2h, b2f, 0, N, planeB);

  // ---- Predictor: one fully fused pass over all 200000 pairs ----
  gemm_pred_fused<<<M2 / 64, 256, 0, stream>>>(planeB, psrc, pdst, nsrc, ndst, P,
                                               wp1h, bp1f, wp2h, bp2f, wp3f, bp3f,
                                               d_out, flagp);
}